// Round 5
// baseline (12474.650 us; speedup 1.0000x reference)
//
#include <hip/hip_runtime.h>

#define H 512
#define NB 256
#define OBS 128
#define LSTEPS 512
#define NPHASE (LSTEPS + 4)
#define NWG 256
#define PLANE (NB * H)
typedef unsigned long long u64;

// fc_Wt[l][k][h] = fc_W[l][h][k];  enc_Wt[k][h] = enc_W[h][k]
__global__ __launch_bounds__(256) void prep_weights(const float* __restrict__ enc_W,
                                                    const float* __restrict__ fc_W,
                                                    float* __restrict__ enc_Wt,
                                                    float* __restrict__ fc_Wt) {
    int idx = blockIdx.x * 256 + threadIdx.x;
    int stride = gridDim.x * 256;
    for (int i = idx; i < 4 * H * H; i += stride) {
        int l = i >> 18;
        int k = (i >> 9) & 511;
        int h = i & 511;
        fc_Wt[i] = fc_W[l * H * H + h * H + k];
    }
    for (int i = idx; i < OBS * H; i += stride) {
        int k = i >> 9;
        int h = i & 511;
        enc_Wt[i] = enc_W[h * OBS + k];
    }
}

// gather one mask word's set bits (ascending), 2 extractions per wave-iteration
#define GATHER(WW, KBASE)                                                          \
    {                                                                              \
        u64 rem = (WW);                                                            \
        while (__any((int)(rem != 0ull))) {                                        \
            int b0 = -1, b1 = -1;                                                  \
            if (rem) { b0 = __builtin_ctzll(rem); rem &= rem - 1; }                \
            if (rem) { b1 = __builtin_ctzll(rem); rem &= rem - 1; }                \
            if (b0 >= 0) {                                                         \
                const float4 wv = *(const float4*)&Wsh[(KBASE) + b0][4 * hq];      \
                acc.x += wv.x; acc.y += wv.y; acc.z += wv.z; acc.w += wv.w;        \
            }                                                                      \
            if (b1 >= 0) {                                                         \
                const float4 wv = *(const float4*)&Wsh[(KBASE) + b1][4 * hq];      \
                acc.x += wv.x; acc.y += wv.y; acc.z += wv.z; acc.w += wv.w;        \
            }                                                                      \
        }                                                                          \
    }

__global__ __launch_bounds__(256, 1) void snn_persistent(
    const float* __restrict__ x,        // [512][256][128]
    const float* __restrict__ mem0,     // [5][256][512]
    const float* __restrict__ enc_b,    // [512]
    const float* __restrict__ fc_b,     // [4][512]
    const float* __restrict__ enc_Wt,   // [128][512] k-major
    const float* __restrict__ fc_Wt,    // [4][512][512] k-major
    u64* __restrict__ masks,            // [4 cons-layer][2 parity][256 n][8 words]
    unsigned int* __restrict__ ctr,     // single barrier counter
    float* __restrict__ out)            // [512][256][512] spikes + [5][256][512] mem
{
    __shared__ float Wsh[512][64];          // 128 KB persistent weight slice
    __shared__ float Xsh[8][128];           // 4 KB enc x tile
    __shared__ u64  Msh[32][8];             // 2 KB staged masks
    __shared__ unsigned char PackB[32][16]; // fc spike nibbles
    __shared__ unsigned char EPackB[8][32]; // enc spike 2-bit packs

    const int tid = threadIdx.x;
    const int wg  = blockIdx.x;
    const int wave = tid >> 6;
    const int lane = tid & 63;

    // fc role: layer, h-slice (64), n-group (32)
    const int layer = wg >> 6;
    const int hs = (wg >> 3) & 7;
    const int g  = wg & 7;
    const int h0 = hs << 6;
    const int n0 = g << 5;
    const int ng = lane >> 4;     // 0..3 n-subgroup
    const int hq = lane & 15;     // h-quad

    // enc role: 8 n x 64 h sliver
    const int en0 = (wg & 31) << 3;
    const int eh0 = (wg >> 5) << 6;
    const int ng2 = lane >> 5;    // 0..1
    const int hp  = lane & 31;    // h-pair
    const int enl = 2 * wave + ng2;   // 0..7 local n
    const int en  = en0 + enl;
    const int eh  = eh0 + 2 * hp;

    // ---------- one-time W staging ----------
    const float* Wl = fc_Wt + (size_t)layer * H * H;
    #pragma unroll
    for (int i = 0; i < 32; ++i) {
        int id = tid + 256 * i;         // 8192 float4 = 512 rows x 16
        int row = id >> 4, c4 = id & 15;
        *(float4*)&Wsh[row][4 * c4] = *(const float4*)(Wl + (size_t)row * H + h0 + 4 * c4);
    }

    const float4 bfc = *(const float4*)(fc_b + layer * H + h0 + 4 * hq);
    const float2 be2 = *(const float2*)(enc_b + eh);

    const int n_a = n0 + 8 * wave + 2 * ng;
    float4 mem_r0 = *(const float4*)(mem0 + (size_t)(layer + 1) * PLANE + (size_t)n_a * H + h0 + 4 * hq);
    float4 mem_r1 = *(const float4*)(mem0 + (size_t)(layer + 1) * PLANE + (size_t)(n_a + 1) * H + h0 + 4 * hq);
    float2 mem_e  = *(const float2*)(mem0 + (size_t)en * H + eh);

    __syncthreads();

    // ---------- phase loop ----------
    for (int p = 0; p < NPHASE; ++p) {
        const int  t_fc   = p - 1 - layer;
        const bool fc_act = (t_fc >= 0) && (t_fc < LSTEPS);
        const bool enc_act = (p < LSTEPS);

        // ---- stage masks (L3-coherent) + x tile ----
        if (fc_act) {
            const u64* msrc = masks + (size_t)(layer * 2 + ((p + 1) & 1)) * (NB * 8);
            u64 v = __hip_atomic_load(msrc + (size_t)(n0 + (tid >> 3)) * 8 + (tid & 7),
                                      __ATOMIC_RELAXED, __HIP_MEMORY_SCOPE_AGENT);
            Msh[tid >> 3][tid & 7] = v;
        }
        if (enc_act) {
            const float* xt = x + (size_t)p * NB * OBS;
            int row = tid >> 5, c4 = tid & 31;
            *(float4*)&Xsh[row][4 * c4] = *(const float4*)(xt + (size_t)(en0 + row) * OBS + 4 * c4);
        }
        __syncthreads();

        // ---- encoder (dense f32, same ascending-k chain as before) ----
        if (enc_act) {
            float2 eacc = make_float2(0.f, 0.f);
            #pragma unroll 8
            for (int k2 = 0; k2 < 64; ++k2) {
                float2 xv = *(const float2*)&Xsh[enl][2 * k2];
                float2 w0 = *(const float2*)(enc_Wt + (size_t)(2 * k2) * H + eh);
                float2 w1 = *(const float2*)(enc_Wt + (size_t)(2 * k2 + 1) * H + eh);
                eacc.x += xv.x * w0.x; eacc.y += xv.x * w0.y;
                eacc.x += xv.y * w1.x; eacc.y += xv.y * w1.y;
            }
            float m0, m1;
            {
                float inp = eacc.x + be2.x; float mp = mem_e.x;
                float reset = (mp > 1.0f) ? 1.0f : 0.0f;
                m0 = 0.9f * mp + inp - reset; mem_e.x = m0;
            }
            {
                float inp = eacc.y + be2.y; float mp = mem_e.y;
                float reset = (mp > 1.0f) ? 1.0f : 0.0f;
                m1 = 0.9f * mp + inp - reset; mem_e.y = m1;
            }
            EPackB[enl][hp] = (unsigned char)((m0 > 1.0f ? 1 : 0) | (m1 > 1.0f ? 2 : 0));
        }

        // ---- fc sparse gather (bitwise-exact vs dense ascending chain) ----
        if (fc_act) {
            #pragma unroll
            for (int r = 0; r < 2; ++r) {
                const int nl = 8 * wave + 2 * ng + r;
                float4 acc = make_float4(0.f, 0.f, 0.f, 0.f);
                u64 w0 = Msh[nl][0], w1 = Msh[nl][1], w2 = Msh[nl][2], w3 = Msh[nl][3];
                u64 w4 = Msh[nl][4], w5 = Msh[nl][5], w6 = Msh[nl][6], w7 = Msh[nl][7];
                GATHER(w0,   0) GATHER(w1,  64) GATHER(w2, 128) GATHER(w3, 192)
                GATHER(w4, 256) GATHER(w5, 320) GATHER(w6, 384) GATHER(w7, 448)

                float4 mp4 = (r == 0) ? mem_r0 : mem_r1;
                float4 mnew;
                {
                    float inp = acc.x + bfc.x; float mp = mp4.x;
                    float reset = (mp > 1.0f) ? 1.0f : 0.0f;
                    mnew.x = 0.9f * mp + inp - reset;
                }
                {
                    float inp = acc.y + bfc.y; float mp = mp4.y;
                    float reset = (mp > 1.0f) ? 1.0f : 0.0f;
                    mnew.y = 0.9f * mp + inp - reset;
                }
                {
                    float inp = acc.z + bfc.z; float mp = mp4.z;
                    float reset = (mp > 1.0f) ? 1.0f : 0.0f;
                    mnew.z = 0.9f * mp + inp - reset;
                }
                {
                    float inp = acc.w + bfc.w; float mp = mp4.w;
                    float reset = (mp > 1.0f) ? 1.0f : 0.0f;
                    mnew.w = 0.9f * mp + inp - reset;
                }
                if (r == 0) mem_r0 = mnew; else mem_r1 = mnew;

                if (layer < 3) {
                    PackB[nl][hq] = (unsigned char)((mnew.x > 1.0f ? 1 : 0) |
                                                    (mnew.y > 1.0f ? 2 : 0) |
                                                    (mnew.z > 1.0f ? 4 : 0) |
                                                    (mnew.w > 1.0f ? 8 : 0));
                } else {
                    float4 s4;
                    s4.x = (mnew.x > 1.0f) ? 1.0f : 0.0f;
                    s4.y = (mnew.y > 1.0f) ? 1.0f : 0.0f;
                    s4.z = (mnew.z > 1.0f) ? 1.0f : 0.0f;
                    s4.w = (mnew.w > 1.0f) ? 1.0f : 0.0f;
                    *(float4*)(out + (size_t)t_fc * PLANE + (size_t)(n0 + nl) * H + h0 + 4 * hq) = s4;
                }
            }
        }
        __syncthreads();   // pack bytes visible

        // ---- packers -> L3-coherent mask stores ----
        if (fc_act && layer < 3 && tid < 32) {
            uint4 bb = *(const uint4*)&PackB[tid][0];
            u64 word = 0;
            unsigned int v;
            v = bb.x; word |= (u64)((v & 0xFu) | ((v >> 8) & 0xFu) << 4 | ((v >> 16) & 0xFu) << 8 | ((v >> 24) & 0xFu) << 12);
            v = bb.y; word |= (u64)((v & 0xFu) | ((v >> 8) & 0xFu) << 4 | ((v >> 16) & 0xFu) << 8 | ((v >> 24) & 0xFu) << 12) << 16;
            v = bb.z; word |= (u64)((v & 0xFu) | ((v >> 8) & 0xFu) << 4 | ((v >> 16) & 0xFu) << 8 | ((v >> 24) & 0xFu) << 12) << 32;
            v = bb.w; word |= (u64)((v & 0xFu) | ((v >> 8) & 0xFu) << 4 | ((v >> 16) & 0xFu) << 8 | ((v >> 24) & 0xFu) << 12) << 48;
            u64* mdst = masks + (size_t)((layer + 1) * 2 + (p & 1)) * (NB * 8);
            __hip_atomic_store(mdst + (size_t)(n0 + tid) * 8 + hs, word,
                               __ATOMIC_RELAXED, __HIP_MEMORY_SCOPE_AGENT);
        }
        if (enc_act && tid < 8) {
            const uint4* eb = (const uint4*)&EPackB[tid][0];
            uint4 b0 = eb[0], b1 = eb[1];
            u64 word = 0;
            unsigned int v;
            v = b0.x; word |= (u64)((v & 3u) | ((v >> 8) & 3u) << 2 | ((v >> 16) & 3u) << 4 | ((v >> 24) & 3u) << 6);
            v = b0.y; word |= (u64)((v & 3u) | ((v >> 8) & 3u) << 2 | ((v >> 16) & 3u) << 4 | ((v >> 24) & 3u) << 6) << 8;
            v = b0.z; word |= (u64)((v & 3u) | ((v >> 8) & 3u) << 2 | ((v >> 16) & 3u) << 4 | ((v >> 24) & 3u) << 6) << 16;
            v = b0.w; word |= (u64)((v & 3u) | ((v >> 8) & 3u) << 2 | ((v >> 16) & 3u) << 4 | ((v >> 24) & 3u) << 6) << 24;
            v = b1.x; word |= (u64)((v & 3u) | ((v >> 8) & 3u) << 2 | ((v >> 16) & 3u) << 4 | ((v >> 24) & 3u) << 6) << 32;
            v = b1.y; word |= (u64)((v & 3u) | ((v >> 8) & 3u) << 2 | ((v >> 16) & 3u) << 4 | ((v >> 24) & 3u) << 6) << 40;
            v = b1.z; word |= (u64)((v & 3u) | ((v >> 8) & 3u) << 2 | ((v >> 16) & 3u) << 4 | ((v >> 24) & 3u) << 6) << 48;
            v = b1.w; word |= (u64)((v & 3u) | ((v >> 8) & 3u) << 2 | ((v >> 16) & 3u) << 4 | ((v >> 24) & 3u) << 6) << 56;
            u64* mdst = masks + (size_t)(p & 1) * (NB * 8);   // consumer layer 0
            __hip_atomic_store(mdst + (size_t)(en0 + tid) * 8 + (wg >> 5), word,
                               __ATOMIC_RELAXED, __HIP_MEMORY_SCOPE_AGENT);
        }

        // ---- grid barrier: single monotone counter, 1 poller per WG ----
        asm volatile("s_waitcnt vmcnt(0)" ::: "memory");   // own sc1 stores at L3
        __syncthreads();                                   // all threads' stores drained
        if (tid == 0) {
            __hip_atomic_fetch_add(ctr, 1u, __ATOMIC_RELAXED, __HIP_MEMORY_SCOPE_AGENT);
            const unsigned int target = (unsigned int)(NWG * (p + 1));
            while (__hip_atomic_load(ctr, __ATOMIC_RELAXED, __HIP_MEMORY_SCOPE_AGENT) < target)
                __builtin_amdgcn_s_sleep(8);
        }
        __syncthreads();                                   // release whole WG
    }

    // ---------- final membrane state ----------
    float* outm = out + (size_t)LSTEPS * PLANE;
    *(float2*)(outm + (size_t)en * H + eh) = mem_e;
    *(float4*)(outm + (size_t)(layer + 1) * PLANE + (size_t)n_a * H + h0 + 4 * hq) = mem_r0;
    *(float4*)(outm + (size_t)(layer + 1) * PLANE + (size_t)(n_a + 1) * H + h0 + 4 * hq) = mem_r1;
}

extern "C" void kernel_launch(void* const* d_in, const int* in_sizes, int n_in,
                              void* d_out, int out_size, void* d_ws, size_t ws_size,
                              hipStream_t stream) {
    const float* x     = (const float*)d_in[0];
    const float* mem0  = (const float*)d_in[1];
    const float* enc_W = (const float*)d_in[2];
    const float* enc_b = (const float*)d_in[3];
    const float* fc_W  = (const float*)d_in[4];
    const float* fc_b  = (const float*)d_in[5];
    float* out = (float*)d_out;

    float* fc_Wt  = (float*)d_ws;                     // 4*512*512 f32 = 4 MB
    float* enc_Wt = fc_Wt + 4 * H * H;                // 128*512 f32 = 256 KB
    u64*   masks  = (u64*)(enc_Wt + OBS * H);         // 8 planes * 2048 u64 = 128 KB
    unsigned int* ctr = (unsigned int*)(masks + 8 * (size_t)NB * 8);

    hipMemsetAsync(ctr, 0, 1024, stream);
    prep_weights<<<dim3(512), dim3(256), 0, stream>>>(enc_W, fc_W, enc_Wt, fc_Wt);
    snn_persistent<<<dim3(NWG), dim3(256), 0, stream>>>(
        x, mem0, enc_b, fc_b, enc_Wt, fc_Wt, masks, ctr, out);
}

// Round 6
// 9295.559 us; speedup vs baseline: 1.3420x; 1.3420x over previous
//
#include <hip/hip_runtime.h>

#define H 512
#define NB 256
#define OBS 128
#define LSTEPS 512
#define TB 4                      // timesteps per phase
#define NTB (LSTEPS / TB)         // 128 timestep-blocks
#define NPHASE (NTB + 4)          // 132 phases
#define NWG 256
#define PLANE (NB * H)
#define PLSZ ((size_t)TB * NB * 8)   // u64 per mask plane
typedef unsigned long long u64;

// fc_Wt[l][k][h] = fc_W[l][h][k];  enc_Wt[k][h] = enc_W[h][k]
__global__ __launch_bounds__(256) void prep_weights(const float* __restrict__ enc_W,
                                                    const float* __restrict__ fc_W,
                                                    float* __restrict__ enc_Wt,
                                                    float* __restrict__ fc_Wt) {
    int idx = blockIdx.x * 256 + threadIdx.x;
    int stride = gridDim.x * 256;
    for (int i = idx; i < 4 * H * H; i += stride) {
        int l = i >> 18;
        int k = (i >> 9) & 511;
        int h = i & 511;
        fc_Wt[i] = fc_W[l * H * H + h * H + k];
    }
    for (int i = idx; i < OBS * H; i += stride) {
        int k = i >> 9;
        int h = i & 511;
        enc_Wt[i] = enc_W[h * OBS + k];
    }
}

// gather one mask word's set bits (ascending), 2 extractions per wave-iteration
#define GATHER(WW, KBASE)                                                          \
    {                                                                              \
        u64 rem = (WW);                                                            \
        while (__any((int)(rem != 0ull))) {                                        \
            int b0 = -1, b1 = -1;                                                  \
            if (rem) { b0 = __builtin_ctzll(rem); rem &= rem - 1; }                \
            if (rem) { b1 = __builtin_ctzll(rem); rem &= rem - 1; }                \
            if (b0 >= 0) {                                                         \
                const float4 wv = *(const float4*)&Wsh[(KBASE) + b0][4 * hq];      \
                acc.x += wv.x; acc.y += wv.y; acc.z += wv.z; acc.w += wv.w;        \
            }                                                                      \
            if (b1 >= 0) {                                                         \
                const float4 wv = *(const float4*)&Wsh[(KBASE) + b1][4 * hq];      \
                acc.x += wv.x; acc.y += wv.y; acc.z += wv.z; acc.w += wv.w;        \
            }                                                                      \
        }                                                                          \
    }

__global__ __launch_bounds__(256, 1) void snn_persistent(
    const float* __restrict__ x,        // [512][256][128]
    const float* __restrict__ mem0,     // [5][256][512]
    const float* __restrict__ enc_b,    // [512]
    const float* __restrict__ fc_b,     // [4][512]
    const float* __restrict__ enc_Wt,   // [128][512] k-major
    const float* __restrict__ fc_Wt,    // [4][512][512] k-major
    u64* __restrict__ masks,            // [4 cons][2 parity][TB][256 n][8 w]
    int* __restrict__ bar,              // slots[256] | done[32] | rel[256]
    float* __restrict__ out)            // [512][256][512] spikes + [5][256][512] mem
{
    __shared__ float Wsh[512][64];            // 128 KB persistent weight slice
    __shared__ float Xsh[TB][8][128];         // 16 KB enc x tiles
    __shared__ u64  Msh[TB][32][8];           // 8 KB staged masks
    __shared__ unsigned char PackB[TB][32][16];  // 2 KB fc spike nibbles
    __shared__ unsigned char EPackB[TB][8][32];  // 1 KB enc spike 2-bit packs

    const int tid = threadIdx.x;
    const int wg  = blockIdx.x;
    const int wave = tid >> 6;
    const int lane = tid & 63;

    // fc role: layer, h-slice (64), n-group (32)
    const int layer = wg >> 6;
    const int hs = (wg >> 3) & 7;
    const int g  = wg & 7;
    const int h0 = hs << 6;
    const int n0 = g << 5;
    const int ng = lane >> 4;     // 0..3 n-subgroup
    const int hq = lane & 15;     // h-quad

    // enc role: 8 n x 64 h sliver
    const int en0 = (wg & 31) << 3;
    const int eh0 = (wg >> 5) << 6;
    const int ng2 = lane >> 5;    // 0..1
    const int hp  = lane & 31;    // h-pair
    const int enl = 2 * wave + ng2;   // 0..7 local n
    const int en  = en0 + enl;
    const int eh  = eh0 + 2 * hp;

    // barrier roles
    int* slots = bar;             // [8 grp][32]
    int* done  = bar + 256;       // [8] in one line
    int* rel   = bar + 288;       // [8 grp][32], word 0 used
    const int grp = wg & 7;
    const int gidx = wg >> 3;

    // ---------- one-time W staging ----------
    const float* Wl = fc_Wt + (size_t)layer * H * H;
    #pragma unroll
    for (int i = 0; i < 32; ++i) {
        int id = tid + 256 * i;
        int row = id >> 4, c4 = id & 15;
        *(float4*)&Wsh[row][4 * c4] = *(const float4*)(Wl + (size_t)row * H + h0 + 4 * c4);
    }

    const float4 bfc = *(const float4*)(fc_b + layer * H + h0 + 4 * hq);
    const float2 be2 = *(const float2*)(enc_b + eh);

    const int n_a = n0 + 8 * wave + 2 * ng;
    float4 mem_r0 = *(const float4*)(mem0 + (size_t)(layer + 1) * PLANE + (size_t)n_a * H + h0 + 4 * hq);
    float4 mem_r1 = *(const float4*)(mem0 + (size_t)(layer + 1) * PLANE + (size_t)(n_a + 1) * H + h0 + 4 * hq);
    float2 mem_e  = *(const float2*)(mem0 + (size_t)en * H + eh);

    __syncthreads();

    // ---------- phase loop ----------
    for (int p = 0; p < NPHASE; ++p) {
        const int  tb_fc  = p - 1 - layer;
        const bool fc_act = (tb_fc >= 0) && (tb_fc < NTB);
        const bool enc_act = (p < NTB);

        // ---- stage masks (L3-coherent) + x tiles ----
        if (fc_act) {
            const u64* msrc = masks + (size_t)(layer * 2 + ((p + 1) & 1)) * PLSZ;
            const int n_l = tid >> 3, w = tid & 7;
            #pragma unroll
            for (int tt = 0; tt < TB; ++tt) {
                u64 v = __hip_atomic_load(msrc + ((size_t)tt * NB + n0 + n_l) * 8 + w,
                                          __ATOMIC_RELAXED, __HIP_MEMORY_SCOPE_AGENT);
                Msh[tt][n_l][w] = v;
            }
        }
        if (enc_act) {
            const float* xt = x + (size_t)(TB * p) * NB * OBS;
            const int row = tid >> 5, c4 = tid & 31;
            #pragma unroll
            for (int tt = 0; tt < TB; ++tt)
                *(float4*)&Xsh[tt][row][4 * c4] =
                    *(const float4*)(xt + (size_t)tt * NB * OBS + (size_t)(en0 + row) * OBS + 4 * c4);
        }
        __syncthreads();

        // ---- encoder: k-outer, 4 accumulators; then 4 sequential LIF steps ----
        if (enc_act) {
            float2 ea[TB];
            #pragma unroll
            for (int tt = 0; tt < TB; ++tt) ea[tt] = make_float2(0.f, 0.f);
            #pragma unroll 4
            for (int k2 = 0; k2 < 64; ++k2) {
                float2 w0 = *(const float2*)(enc_Wt + (size_t)(2 * k2) * H + eh);
                float2 w1 = *(const float2*)(enc_Wt + (size_t)(2 * k2 + 1) * H + eh);
                #pragma unroll
                for (int tt = 0; tt < TB; ++tt) {
                    float2 xv = *(const float2*)&Xsh[tt][enl][2 * k2];
                    ea[tt].x += xv.x * w0.x; ea[tt].y += xv.x * w0.y;
                    ea[tt].x += xv.y * w1.x; ea[tt].y += xv.y * w1.y;
                }
            }
            #pragma unroll
            for (int tt = 0; tt < TB; ++tt) {
                float m0, m1;
                {
                    float inp = ea[tt].x + be2.x; float mp = mem_e.x;
                    float reset = (mp > 1.0f) ? 1.0f : 0.0f;
                    m0 = 0.9f * mp + inp - reset; mem_e.x = m0;
                }
                {
                    float inp = ea[tt].y + be2.y; float mp = mem_e.y;
                    float reset = (mp > 1.0f) ? 1.0f : 0.0f;
                    m1 = 0.9f * mp + inp - reset; mem_e.y = m1;
                }
                EPackB[tt][enl][hp] = (unsigned char)((m0 > 1.0f ? 1 : 0) | (m1 > 1.0f ? 2 : 0));
            }
        }

        // ---- fc sparse gather x TB (bitwise-exact vs dense ascending chain) ----
        if (fc_act) {
            #pragma unroll
            for (int tt = 0; tt < TB; ++tt) {
                #pragma unroll
                for (int r = 0; r < 2; ++r) {
                    const int nl = 8 * wave + 2 * ng + r;
                    float4 acc = make_float4(0.f, 0.f, 0.f, 0.f);
                    u64 w0 = Msh[tt][nl][0], w1 = Msh[tt][nl][1], w2 = Msh[tt][nl][2], w3 = Msh[tt][nl][3];
                    u64 w4 = Msh[tt][nl][4], w5 = Msh[tt][nl][5], w6 = Msh[tt][nl][6], w7 = Msh[tt][nl][7];
                    GATHER(w0,   0) GATHER(w1,  64) GATHER(w2, 128) GATHER(w3, 192)
                    GATHER(w4, 256) GATHER(w5, 320) GATHER(w6, 384) GATHER(w7, 448)

                    float4 mp4 = (r == 0) ? mem_r0 : mem_r1;
                    float4 mnew;
                    {
                        float inp = acc.x + bfc.x; float mp = mp4.x;
                        float reset = (mp > 1.0f) ? 1.0f : 0.0f;
                        mnew.x = 0.9f * mp + inp - reset;
                    }
                    {
                        float inp = acc.y + bfc.y; float mp = mp4.y;
                        float reset = (mp > 1.0f) ? 1.0f : 0.0f;
                        mnew.y = 0.9f * mp + inp - reset;
                    }
                    {
                        float inp = acc.z + bfc.z; float mp = mp4.z;
                        float reset = (mp > 1.0f) ? 1.0f : 0.0f;
                        mnew.z = 0.9f * mp + inp - reset;
                    }
                    {
                        float inp = acc.w + bfc.w; float mp = mp4.w;
                        float reset = (mp > 1.0f) ? 1.0f : 0.0f;
                        mnew.w = 0.9f * mp + inp - reset;
                    }
                    if (r == 0) mem_r0 = mnew; else mem_r1 = mnew;

                    if (layer < 3) {
                        PackB[tt][nl][hq] = (unsigned char)((mnew.x > 1.0f ? 1 : 0) |
                                                            (mnew.y > 1.0f ? 2 : 0) |
                                                            (mnew.z > 1.0f ? 4 : 0) |
                                                            (mnew.w > 1.0f ? 8 : 0));
                    } else {
                        const int t = TB * tb_fc + tt;
                        float4 s4;
                        s4.x = (mnew.x > 1.0f) ? 1.0f : 0.0f;
                        s4.y = (mnew.y > 1.0f) ? 1.0f : 0.0f;
                        s4.z = (mnew.z > 1.0f) ? 1.0f : 0.0f;
                        s4.w = (mnew.w > 1.0f) ? 1.0f : 0.0f;
                        *(float4*)(out + (size_t)t * PLANE + (size_t)(n0 + nl) * H + h0 + 4 * hq) = s4;
                    }
                }
            }
        }
        __syncthreads();   // pack bytes visible

        // ---- packers -> L3-coherent mask stores ----
        if (fc_act && layer < 3 && tid < 32 * TB) {
            const int tt = tid >> 5, row = tid & 31;
            uint4 bb = *(const uint4*)&PackB[tt][row][0];
            u64 word = 0;
            unsigned int v;
            v = bb.x; word |= (u64)((v & 0xFu) | ((v >> 8) & 0xFu) << 4 | ((v >> 16) & 0xFu) << 8 | ((v >> 24) & 0xFu) << 12);
            v = bb.y; word |= (u64)((v & 0xFu) | ((v >> 8) & 0xFu) << 4 | ((v >> 16) & 0xFu) << 8 | ((v >> 24) & 0xFu) << 12) << 16;
            v = bb.z; word |= (u64)((v & 0xFu) | ((v >> 8) & 0xFu) << 4 | ((v >> 16) & 0xFu) << 8 | ((v >> 24) & 0xFu) << 12) << 32;
            v = bb.w; word |= (u64)((v & 0xFu) | ((v >> 8) & 0xFu) << 4 | ((v >> 16) & 0xFu) << 8 | ((v >> 24) & 0xFu) << 12) << 48;
            u64* mdst = masks + (size_t)((layer + 1) * 2 + (p & 1)) * PLSZ;
            __hip_atomic_store(mdst + ((size_t)tt * NB + n0 + row) * 8 + hs, word,
                               __ATOMIC_RELAXED, __HIP_MEMORY_SCOPE_AGENT);
        }
        if (enc_act && tid < 8 * TB) {
            const int tt = tid >> 3, row = tid & 7;
            const uint4* eb = (const uint4*)&EPackB[tt][row][0];
            uint4 b0 = eb[0], b1 = eb[1];
            u64 word = 0;
            unsigned int v;
            v = b0.x; word |= (u64)((v & 3u) | ((v >> 8) & 3u) << 2 | ((v >> 16) & 3u) << 4 | ((v >> 24) & 3u) << 6);
            v = b0.y; word |= (u64)((v & 3u) | ((v >> 8) & 3u) << 2 | ((v >> 16) & 3u) << 4 | ((v >> 24) & 3u) << 6) << 8;
            v = b0.z; word |= (u64)((v & 3u) | ((v >> 8) & 3u) << 2 | ((v >> 16) & 3u) << 4 | ((v >> 24) & 3u) << 6) << 16;
            v = b0.w; word |= (u64)((v & 3u) | ((v >> 8) & 3u) << 2 | ((v >> 16) & 3u) << 4 | ((v >> 24) & 3u) << 6) << 24;
            v = b1.x; word |= (u64)((v & 3u) | ((v >> 8) & 3u) << 2 | ((v >> 16) & 3u) << 4 | ((v >> 24) & 3u) << 6) << 32;
            v = b1.y; word |= (u64)((v & 3u) | ((v >> 8) & 3u) << 2 | ((v >> 16) & 3u) << 4 | ((v >> 24) & 3u) << 6) << 40;
            v = b1.z; word |= (u64)((v & 3u) | ((v >> 8) & 3u) << 2 | ((v >> 16) & 3u) << 4 | ((v >> 24) & 3u) << 6) << 48;
            v = b1.w; word |= (u64)((v & 3u) | ((v >> 8) & 3u) << 2 | ((v >> 16) & 3u) << 4 | ((v >> 24) & 3u) << 6) << 56;
            u64* mdst = masks + (size_t)(p & 1) * PLSZ;
            __hip_atomic_store(mdst + ((size_t)tt * NB + en0 + row) * 8 + (wg >> 5), word,
                               __ATOMIC_RELAXED, __HIP_MEMORY_SCOPE_AGENT);
        }

        // ---- hierarchical store-based grid barrier (no same-address RMW) ----
        asm volatile("s_waitcnt vmcnt(0)" ::: "memory");   // all sc1 stores at L3
        __syncthreads();                                   // whole WG drained
        if (tid == 0) {
            const int target = p + 1;
            __hip_atomic_store(slots + grp * 32 + gidx, target,
                               __ATOMIC_RELAXED, __HIP_MEMORY_SCOPE_AGENT);
            if (gidx == 0) {
                // group leader: scan my group's 32 slots (one cache line)
                for (;;) {
                    int all = 1;
                    #pragma unroll
                    for (int i = 0; i < 32; ++i) {
                        int v = __hip_atomic_load(slots + grp * 32 + i,
                                                  __ATOMIC_RELAXED, __HIP_MEMORY_SCOPE_AGENT);
                        all &= (v >= target);
                    }
                    if (all) break;
                }
                __hip_atomic_store(done + grp, target,
                                   __ATOMIC_RELAXED, __HIP_MEMORY_SCOPE_AGENT);
                for (;;) {
                    int all = 1;
                    #pragma unroll
                    for (int i = 0; i < 8; ++i) {
                        int v = __hip_atomic_load(done + i,
                                                  __ATOMIC_RELAXED, __HIP_MEMORY_SCOPE_AGENT);
                        all &= (v >= target);
                    }
                    if (all) break;
                }
                __hip_atomic_store(rel + grp * 32, target,
                                   __ATOMIC_RELAXED, __HIP_MEMORY_SCOPE_AGENT);
            } else {
                while (__hip_atomic_load(rel + grp * 32,
                                         __ATOMIC_RELAXED, __HIP_MEMORY_SCOPE_AGENT) < target)
                    __builtin_amdgcn_s_sleep(1);
            }
        }
        __syncthreads();
    }

    // ---------- final membrane state ----------
    float* outm = out + (size_t)LSTEPS * PLANE;
    *(float2*)(outm + (size_t)en * H + eh) = mem_e;
    *(float4*)(outm + (size_t)(layer + 1) * PLANE + (size_t)n_a * H + h0 + 4 * hq) = mem_r0;
    *(float4*)(outm + (size_t)(layer + 1) * PLANE + (size_t)(n_a + 1) * H + h0 + 4 * hq) = mem_r1;
}

extern "C" void kernel_launch(void* const* d_in, const int* in_sizes, int n_in,
                              void* d_out, int out_size, void* d_ws, size_t ws_size,
                              hipStream_t stream) {
    const float* x     = (const float*)d_in[0];
    const float* mem0  = (const float*)d_in[1];
    const float* enc_W = (const float*)d_in[2];
    const float* enc_b = (const float*)d_in[3];
    const float* fc_W  = (const float*)d_in[4];
    const float* fc_b  = (const float*)d_in[5];
    float* out = (float*)d_out;

    float* fc_Wt  = (float*)d_ws;                     // 4 MB
    float* enc_Wt = fc_Wt + 4 * H * H;                // 256 KB
    u64*   masks  = (u64*)(enc_Wt + OBS * H);         // 8 planes * TB*256*8 u64 = 512 KB
    int*   bar    = (int*)(masks + 8 * PLSZ);         // slots 256 | done 32 | rel 256

    hipMemsetAsync(bar, 0, 544 * sizeof(int), stream);
    prep_weights<<<dim3(512), dim3(256), 0, stream>>>(enc_W, fc_W, enc_Wt, fc_Wt);
    snn_persistent<<<dim3(NWG), dim3(256), 0, stream>>>(
        x, mem0, enc_b, fc_b, enc_Wt, fc_Wt, masks, bar, out);
}